// Round 2
// baseline (59.144 us; speedup 1.0000x reference)
//
#include <hip/hip_runtime.h>

// Output = one_hot(arange(N), N) @ W = I @ W = W.  Pure copy of W.
// Reference dtypes are float32 -> d_in[0] and d_out are float* per harness
// contract. out_size = 16384*128 = 2,097,152 f32 elements = 8 MiB.
// Copy 16 B per lane (uint4 = 4 f32): 524,288 threads, fully coalesced.
// Round-1 bug: divided by 8 (bf16 assumption) and copied only half the
// buffer -> second half stayed zero -> absmax == max|W|. Fixed: /4.

__global__ __launch_bounds__(256)
void copy_w_kernel(const uint4* __restrict__ src, uint4* __restrict__ dst) {
    const int i = blockIdx.x * blockDim.x + threadIdx.x;
    dst[i] = src[i];
}

extern "C" void kernel_launch(void* const* d_in, const int* in_sizes, int n_in,
                              void* d_out, int out_size, void* d_ws, size_t ws_size,
                              hipStream_t stream) {
    const uint4* src = (const uint4*)d_in[0];
    uint4* dst = (uint4*)d_out;
    const int n_vec = out_size / 4;          // 2,097,152 f32 / 4 = 524,288 uint4
    const int block = 256;
    const int grid = (n_vec + block - 1) / block;  // 2048 blocks
    copy_w_kernel<<<grid, block, 0, stream>>>(src, dst);
}

// Round 3
// 57.552 us; speedup vs baseline: 1.0277x; 1.0277x over previous
//
#include <hip/hip_runtime.h>

// Output = one_hot(arange(N), N) @ W = I @ W = W.  Pure copy of W (f32).
// 16384*128 f32 = 8 MiB. Round-2 kernel copy was correct and ~3 us (absent
// from rocprof top-5; all top-5 are the harness's 268 MB 0xAA ws-poison fills
// at ~42 us each). dur_us=59 is harness-dominated. This round: replace the
// copy kernel with a graph-capturable hipMemcpyAsync d2d (explicitly allowed
// by the harness contract) to shave kernel-dispatch overhead — and as a probe:
// if dur_us is unchanged, the floor is the harness reset path, not us.

extern "C" void kernel_launch(void* const* d_in, const int* in_sizes, int n_in,
                              void* d_out, int out_size, void* d_ws, size_t ws_size,
                              hipStream_t stream) {
    const size_t nbytes = (size_t)out_size * sizeof(float);  // 8 MiB
    hipMemcpyAsync(d_out, d_in[0], nbytes, hipMemcpyDeviceToDevice, stream);
}